// Round 1
// baseline (6721.265 us; speedup 1.0000x reference)
//
#include <hip/hip_runtime.h>
#include <math.h>

// ---------------- problem constants ----------------
#define NB 32      // molecules
#define NA 24      // atoms
#define EMBED 32
#define NBASIS 10
#define C_FEAT 128 // 24 + 12*3 + 8*5 + 4*7
#define C_OUT 152  // 48 + 12*3 + 8*5 + 4*7

// ---------------- constexpr path table ----------------
struct PathC { int li, mi, lo, mo, lf, woff; float scale; };
struct PTable { PathC p[72]; };

constexpr double csqrt_(double x){ double g = x < 1.0 ? 1.0 : x; for(int i=0;i<80;++i) g = 0.5*(g + x/g); return g; }

constexpr PTable build_paths(){
  PTable t{};
  int off=0, n=0;
  for(int layer=0; layer<3; ++layer){
    const int nin = (layer==0)?1:4;
    for(int ii=0; ii<nin; ++ii){
      const int mi = (layer==0)?32:((int[4]){24,12,8,4})[ii];
      const int li = (layer==0)?0:ii;
      const int mo_a[4]={48,12,8,4};
      for(int oo=0; oo<4; ++oo){
        int mo=mo_a[oo], lo=oo;
        int lfmin = li>lo? li-lo : lo-li;
        int lfmax = (li+lo)<3 ? (li+lo) : 3;
        for(int lf=lfmin; lf<=lfmax; ++lf){
          t.p[n].li=li; t.p[n].mi=mi; t.p[n].lo=lo; t.p[n].mo=mo; t.p[n].lf=lf; t.p[n].woff=off;
          t.p[n].scale=(float)(1.0/(csqrt_(10.0*mi)*csqrt_(18.0)));
          off += 10*mo*mi; ++n;
        }
      }
    }
  }
  return t;
}
constexpr int total_woff(){
  PTable t = build_paths();
  return t.p[71].woff + 10*t.p[71].mo*t.p[71].mi;
}
static_assert(total_woff()==114880, "weight offset mismatch");
__constant__ PTable c_paths = build_paths();

// ---------------- CG init (fp64, every launch; deterministic) ----------------
__device__ double dfact(int n){ double r=1.0; for(int i=2;i<=n;++i) r*=(double)i; return r; }

__device__ double cg_coef(int j1,int m1,int j2,int m2,int j3,int m3){
  if (m1+m2 != m3) return 0.0;
  double pre = sqrt((2.0*j3+1.0) * dfact(j3+j1-j2)*dfact(j3-j1+j2)*dfact(j1+j2-j3)/dfact(j1+j2+j3+1));
  pre *= sqrt(dfact(j3+m3)*dfact(j3-m3)*dfact(j1-m1)*dfact(j1+m1)*dfact(j2-m2)*dfact(j2+m2));
  double s=0.0;
  for(int k=0;k<=j1+j2+j3;++k){
    int a1=k, a2=j1+j2-j3-k, a3=j1-m1-k, a4=j2+m2-k, a5=j3-j2+m1+k, a6=j3-j1-m2+k;
    if(a1<0||a2<0||a3<0||a4<0||a5<0||a6<0) continue;
    double d = dfact(a1)*dfact(a2)*dfact(a3)*dfact(a4)*dfact(a5)*dfact(a6);
    s += ((k&1)? -1.0:1.0)/d;
  }
  return pre*s;
}

__device__ void fill_u(int l, double* ur, double* ui){
  for(int i=0;i<49;++i){ ur[i]=0.0; ui[i]=0.0; }
  const double s = 0.70710678118654752440;
  for(int m=-l;m<=l;++m){
    if(m==0){ ur[l*7+l]=1.0; }
    else if(m>0){
      ur[(m+l)*7+(m+l)] = ((m&1)? -s : s);
      ur[(m+l)*7+(l-m)] = s;
    } else {
      int a=-m;
      ui[(m+l)*7+(m+l)] = s;            //  1j*s
      ui[(m+l)*7+(a+l)] = ((a&1)? s : -s); // -1j*(-1)^a*s
    }
  }
}

// one block per path; duplicate keys write identical values (benign)
__global__ void init_cg_kernel(float* __restrict__ cg){
  const PathC pc = c_paths.p[blockIdx.x];
  const int l1=pc.li, l2=pc.lf, l3=pc.lo;
  __shared__ double u1r[49],u1i[49],u2r[49],u2i[49],u3r[49],u3i[49];
  __shared__ double s_tr[343], s_ti[343];
  __shared__ int s_flag;
  if(threadIdx.x==0){ fill_u(l1,u1r,u1i); fill_u(l2,u2r,u2i); fill_u(l3,u3r,u3i); }
  __syncthreads();
  const int d1=2*l1+1,d2=2*l2+1,d3=2*l3+1, ne=d1*d2*d3;
  for(int e=threadIdx.x;e<ne;e+=blockDim.x){
    int a=e/(d2*d3); int r=e-a*d2*d3; int bq=r/d3; int c=r-bq*d3;
    double Tr=0.0, Ti=0.0;
    for(int ic=0;ic<d1;++ic){
      double ar=u1r[a*7+ic], ai=u1i[a*7+ic];
      if(ar==0.0 && ai==0.0) continue;
      for(int jc=0;jc<d2;++jc){
        double br=u2r[bq*7+jc], bi=u2i[bq*7+jc];
        if(br==0.0 && bi==0.0) continue;
        int m1=ic-l1, m2=jc-l2, m3=m1+m2;
        if(m3<-l3||m3>l3) continue;
        int kc=m3+l3;
        double cr=u3r[c*7+kc], ci=-u3i[c*7+kc];
        double cgv=cg_coef(l1,m1,l2,m2,l3,m3);
        double abr=ar*br-ai*bi, abi=ar*bi+ai*br;
        Tr += (abr*cr-abi*ci)*cgv;
        Ti += (abr*ci+abi*cr)*cgv;
      }
    }
    s_tr[e]=Tr; s_ti[e]=Ti;
  }
  __syncthreads();
  if(threadIdx.x==0){
    double sr=0.0, si=0.0;
    for(int e=0;e<ne;++e){ sr+=fabs(s_tr[e]); si+=fabs(s_ti[e]); }
    s_flag = (sr>=si)?1:0;
  }
  __syncthreads();
  const int keybase = ((l1*4+l2)*4+l3)*343;
  for(int e=threadIdx.x;e<ne;e+=blockDim.x){
    int a=e/(d2*d3); int r=e-a*d2*d3; int f=r/d3; int o=r-f*d3;
    cg[keybase + (a*7+f)*7 + o] = (float)(s_flag? s_tr[e] : s_ti[e]);
  }
}

// ---------------- pair kernel: Y[16] + masked rbasis[10] ----------------
__global__ void pair_kernel(const float* __restrict__ pos, const float* __restrict__ maskp,
                            float* __restrict__ Yg, float* __restrict__ rbg){
  int idx = blockIdx.x*blockDim.x + threadIdx.x;
  if(idx >= NB*NA*NA) return;
  int j = idx % NA; int t = idx / NA; int a = t % NA; int b = t / NA;
  const float* pa = pos + (b*NA+a)*3;
  const float* pj = pos + (b*NA+j)*3;
  float dx=pj[0]-pa[0], dy=pj[1]-pa[1], dz=pj[2]-pa[2];
  float r = sqrtf(dx*dx+dy*dy+dz*dz + 1e-12f);
  float inv = 1.f/(r + 1e-9f);
  float x=dx*inv, y=dy*inv, z=dz*inv;
  float r2 = x*x+y*y+z*z;
  float* Yp = Yg + idx*16;
  Yp[0] = 0.28209479177387814f;
  Yp[1] = 0.4886025119029199f*y;
  Yp[2] = 0.4886025119029199f*z;
  Yp[3] = 0.4886025119029199f*x;
  Yp[4] = 1.0925484305920792f*x*y;
  Yp[5] = 1.0925484305920792f*y*z;
  Yp[6] = 0.31539156525252005f*(3.f*z*z - r2);
  Yp[7] = 1.0925484305920792f*x*z;
  Yp[8] = 0.5462742152960396f*(x*x - y*y);
  Yp[9] = 0.5900435899266435f*y*(3.f*x*x - y*y);
  Yp[10]= 2.890611442640554f*x*y*z;
  Yp[11]= 0.4570457994644658f*y*(5.f*z*z - r2);
  Yp[12]= 0.3731763325901154f*z*(5.f*z*z - 3.f*r2);
  Yp[13]= 0.4570457994644658f*x*(5.f*z*z - r2);
  Yp[14]= 1.445305721320277f*z*(x*x - y*y);
  Yp[15]= 0.5900435899266435f*x*(x*x - 3.f*y*y);
  float mk = maskp[b*NA+j];
  float* rp = rbg + idx*10;
  const float w = 5.f/9.f;
  for(int k=0;k<10;++k){
    float ck = 5.f*(float)k/9.f;
    float tt = (r-ck)/w;
    rp[k] = expf(-0.5f*tt*tt)*mk;
  }
}

// ---------------- embed ----------------
__global__ void embed_kernel(const int* __restrict__ z, const float* __restrict__ table,
                             float* __restrict__ f0){
  int idx = blockIdx.x*blockDim.x + threadIdx.x;
  if(idx >= NB*NA*EMBED) return;
  int c = idx & 31; int n = idx >> 5;
  f0[idx] = table[z[n]*EMBED + c];
}

// ---------------- per-layer kernel ----------------
template<int LAYER>
__global__ __launch_bounds__(256) void layer_kernel(
    const float* __restrict__ fin, const float* __restrict__ Yg, const float* __restrict__ rbg,
    const float* __restrict__ radial_w, const float* __restrict__ cg,
    const float* __restrict__ maskp, float* __restrict__ fout)
{
  constexpr int C_IN = (LAYER==0)?32:128;
  constexpr int PBEG = (LAYER==0)?0:(LAYER==1?4:38);
  constexpr int PEND = (LAYER==0)?4:(LAYER==1?38:72);
  constexpr int NIN  = (LAYER==0)?1:4;
  constexpr int DMAX = (LAYER==0)?32:40;
  __shared__ float s_fin[NA*C_IN];
  __shared__ float s_Y[NA*16];
  __shared__ float s_rb[NA*10];
  __shared__ float s_A[160*DMAX];
  __shared__ float s_Q[343];
  __shared__ float s_out[C_OUT];
  __shared__ float s_gate[24];

  const int tid = threadIdx.x;
  const int bid = blockIdx.x;
  const int b = bid / NA, a = bid % NA;

  // cooperative loads (all contiguous)
  for(int i=tid;i<NA*C_IN;i+=256) s_fin[i] = fin[b*NA*C_IN + i];
  {
    const int pbase = (b*NA+a)*NA;
    for(int i=tid;i<NA*16;i+=256) s_Y[i]  = Yg[pbase*16 + i];
    for(int i=tid;i<NA*10;i+=256) s_rb[i] = rbg[pbase*10 + i];
  }

  // output-element ownership
  int lo_t=-1,u_t=0,o_t=0;
  if(tid<48){ lo_t=0; u_t=tid; o_t=0; }
  else if(tid<84){ lo_t=1; int r=tid-48; u_t=r/3; o_t=r-3*u_t; }
  else if(tid<124){ lo_t=2; int r=tid-84; u_t=r/5; o_t=r-5*u_t; }
  else if(tid<152){ lo_t=3; int r=tid-124; u_t=r/7; o_t=r-7*u_t; }
  float acc = 0.f;

  const int mi_arr[4]  = {24,12,8,4};
  const int ci0_arr[4] = {0,24,60,100};

  for(int ii=0; ii<NIN; ++ii){
    const int li  = (LAYER==0)?0:ii;
    const int mi  = (LAYER==0)?32:mi_arr[ii];
    const int ci0 = (LAYER==0)?0:ci0_arr[ii];
    const int dli = 2*li+1;
    const int D   = mi*dli;

    __syncthreads();  // protect s_A before overwrite (and covers initial loads)
    // stage A: A[k][f16][ci] = sum_j rb[j,k]*Y[j,f]*fin[j,ci0+ci]
    for(int idx=tid; idx<160*D; idx+=256){
      int kf = idx / D, ci = idx - kf*D;
      int k = kf>>4, f = kf&15;
      float s=0.f;
      for(int j=0;j<NA;++j) s += s_rb[j*10+k]*s_Y[j*16+f]*s_fin[j*C_IN+ci0+ci];
      s_A[idx]=s;
    }
    __syncthreads();

    for(int p=PBEG;p<PEND;++p){
      const PathC pc = c_paths.p[p];
      if(pc.li != li) continue;          // uniform branch
      const int lf=pc.lf, lo=pc.lo, dlf=2*lf+1, dlo=2*lo+1;
      const int qn = dli*dlf*dlo;
      const int keybase = ((li*4+lf)*4+lo)*343;
      for(int q=tid;q<qn;q+=256){
        int i1=q/(dlf*dlo); int r=q-i1*dlf*dlo; int f=r/dlo; int o=r-f*dlo;
        s_Q[q] = cg[keybase + (i1*7+f)*7 + o];
      }
      __syncthreads();
      if(lo_t == lo){
        const int mo = pc.mo;
        const float* Wp = radial_w + pc.woff;
        const int foff = lf*lf;
        float sum = 0.f;
        for(int k=0;k<10;++k){
          for(int v=0;v<mi;++v){
            float w = Wp[(k*mo+u_t)*mi + v];
            float s = 0.f;
            const float* Ab = &s_A[(k*16+foff)*D + v*dli];
            for(int f=0;f<dlf;++f)
              for(int i=0;i<dli;++i)
                s += Ab[f*D + i] * s_Q[(i*dlf+f)*dlo + o_t];
            sum += w*s;
          }
        }
        acc += pc.scale * sum;
      }
      __syncthreads();
    }
  }

  // gated epilogue
  __syncthreads();
  if(tid < C_OUT) s_out[tid] = acc;
  __syncthreads();
  if(tid < 24) s_gate[tid] = 1.f/(1.f+expf(-s_out[24+tid]));
  __syncthreads();
  const float mval = maskp[b*NA+a];
  for(int c=tid;c<C_FEAT;c+=256){
    float val;
    if(c<24)       { val = fmaxf(s_out[c], 0.f); }
    else if(c<60)  { int r=c-24;  int v=r/3; val = s_out[48+r]  * s_gate[v]; }
    else if(c<100) { int r=c-60;  int v=r/5; val = s_out[84+r]  * s_gate[12+v]; }
    else           { int r=c-100; int v=r/7; val = s_out[124+r] * s_gate[20+v]; }
    fout[(b*NA+a)*C_FEAT + c] = val*mval;
  }
}

// ---------------- launch ----------------
extern "C" void kernel_launch(void* const* d_in, const int* in_sizes, int n_in,
                              void* d_out, int out_size, void* d_ws, size_t ws_size,
                              hipStream_t stream) {
  const int*   z     = (const int*)  d_in[0];
  const float* pos   = (const float*)d_in[1];
  const float* mask  = (const float*)d_in[2];
  const float* table = (const float*)d_in[3];
  const float* rw    = (const float*)d_in[4];
  float* out = (float*)d_out;
  float* ws  = (float*)d_ws;

  float* cg  = ws;                 // 64*343 = 21952
  float* Yg  = cg  + 21952;        // 32*24*24*16 = 294912
  float* rbg = Yg  + 294912;       // 32*24*24*10 = 184320
  float* f0  = rbg + 184320;       // 32*24*32 = 24576
  float* fA  = f0  + 24576;        // 32*24*128 = 98304
  float* fB  = fA  + 98304;        // 32*24*128 = 98304

  init_cg_kernel<<<72, 384, 0, stream>>>(cg);
  embed_kernel<<<(NB*NA*EMBED+255)/256, 256, 0, stream>>>(z, table, f0);
  pair_kernel<<<(NB*NA*NA+255)/256, 256, 0, stream>>>(pos, mask, Yg, rbg);

  layer_kernel<0><<<NB*NA, 256, 0, stream>>>(f0, Yg, rbg, rw, cg, mask, fA);
  layer_kernel<1><<<NB*NA, 256, 0, stream>>>(fA, Yg, rbg, rw, cg, mask, fB);
  layer_kernel<2><<<NB*NA, 256, 0, stream>>>(fB, Yg, rbg, rw, cg, mask, out);
}

// Round 2
// 588.491 us; speedup vs baseline: 11.4212x; 11.4212x over previous
//
#include <hip/hip_runtime.h>
#include <math.h>

// ---------------- problem constants ----------------
#define NB 32      // molecules
#define NA 24      // atoms
#define EMBED 32
#define C_FEAT 128 // 24 + 12*3 + 8*5 + 4*7
#define C_OUT 152  // 48 + 12*3 + 8*5 + 4*7

// ---------------- constexpr path table ----------------
struct PathC { int li, mi, lo, mo, lf, woff, toff, qoff, ci0, obase; float scale; };
struct PTable { PathC p[72]; };

constexpr double csqrt_(double x){ double g = x < 1.0 ? 1.0 : x; for(int i=0;i<80;++i) g = 0.5*(g + x/g); return g; }

constexpr PTable build_paths(){
  PTable t{};
  int off=0, n=0;
  for(int layer=0; layer<3; ++layer){
    int toff=0, qoff=0;
    const int nin = (layer==0)?1:4;
    for(int ii=0; ii<nin; ++ii){
      const int mi_a[4]={24,12,8,4};
      const int ci0_a[4]={0,24,60,100};
      const int mi = (layer==0)?32:mi_a[ii];
      const int li = (layer==0)?0:ii;
      const int ci0 = (layer==0)?0:ci0_a[ii];
      const int mo_a[4]={48,12,8,4};
      const int ob_a[4]={0,48,84,124};
      for(int oo=0; oo<4; ++oo){
        int mo=mo_a[oo], lo=oo;
        int lfmin = li>lo? li-lo : lo-li;
        int lfmax = (li+lo)<3 ? (li+lo) : 3;
        for(int lf=lfmin; lf<=lfmax; ++lf){
          t.p[n].li=li; t.p[n].mi=mi; t.p[n].lo=lo; t.p[n].mo=mo; t.p[n].lf=lf;
          t.p[n].woff=off; t.p[n].toff=toff; t.p[n].qoff=qoff;
          t.p[n].ci0=ci0; t.p[n].obase=ob_a[lo];
          t.p[n].scale=(float)(1.0/(csqrt_(10.0*mi)*csqrt_(18.0)));
          off += 10*mo*mi;
          toff += mi*(2*lo+1);
          qoff += (2*li+1)*(2*lf+1)*(2*lo+1);
          ++n;
        }
      }
    }
  }
  return t;
}
constexpr int total_woff(){
  PTable t = build_paths();
  return t.p[71].woff + 10*t.p[71].mo*t.p[71].mi;
}
static_assert(total_woff()==114880, "weight offset mismatch");
__constant__ PTable c_paths = build_paths();

// ---------------- constexpr work-item tables ----------------
struct ITables {
  unsigned short q0[84],   t0[512],   o0[152];
  unsigned short q12[3436],t12[1460], o12[1236];
  int nq0, nt0, no0, nq12, nt12, no12;
};
constexpr ITables build_items(){
  ITables it{};
  PTable pt = build_paths();
  // layer 0: paths 0..3
  {
    int nq=0,nt=0,no=0;
    for(int p=0;p<4;++p){
      const PathC pc = pt.p[p];
      int dli=2*pc.li+1, dlf=2*pc.lf+1, dlo=2*pc.lo+1;
      for(int i=0;i<dli;++i)for(int f=0;f<dlf;++f)for(int o=0;o<dlo;++o)
        it.q0[nq++]=(unsigned short)((p<<9)|(i<<6)|(f<<3)|o);
      for(int v=0;v<pc.mi;++v)for(int o=0;o<dlo;++o)
        it.t0[nt++]=(unsigned short)((p<<8)|(v<<3)|o);
      for(int u=0;u<pc.mo;++u)for(int o=0;o<dlo;++o)
        it.o0[no++]=(unsigned short)((p<<9)|(u<<3)|o);
    }
    it.nq0=nq; it.nt0=nt; it.no0=no;
  }
  // layers 1/2 share structure: build from paths 4..37, prel = p-4
  {
    int nq=0,nt=0,no=0;
    for(int p=4;p<38;++p){
      const PathC pc = pt.p[p];
      int prel = p-4;
      int dli=2*pc.li+1, dlf=2*pc.lf+1, dlo=2*pc.lo+1;
      for(int i=0;i<dli;++i)for(int f=0;f<dlf;++f)for(int o=0;o<dlo;++o)
        it.q12[nq++]=(unsigned short)((prel<<9)|(i<<6)|(f<<3)|o);
      for(int v=0;v<pc.mi;++v)for(int o=0;o<dlo;++o)
        it.t12[nt++]=(unsigned short)((prel<<8)|(v<<3)|o);
      for(int u=0;u<pc.mo;++u)for(int o=0;o<dlo;++o)
        it.o12[no++]=(unsigned short)((prel<<9)|(u<<3)|o);
    }
    it.nq12=nq; it.nt12=nt; it.no12=no;
  }
  return it;
}
constexpr ITables g_it_chk = build_items();
static_assert(g_it_chk.nq0==84 && g_it_chk.nt0==512 && g_it_chk.no0==152, "l0 counts");
static_assert(g_it_chk.nq12==3436 && g_it_chk.nt12==1460 && g_it_chk.no12==1236, "l12 counts");
__constant__ ITables c_it = build_items();

// ---------------- CG init (fp64, every launch; deterministic) ----------------
__device__ double dfact(int n){ double r=1.0; for(int i=2;i<=n;++i) r*=(double)i; return r; }

__device__ double cg_coef(int j1,int m1,int j2,int m2,int j3,int m3){
  if (m1+m2 != m3) return 0.0;
  double pre = sqrt((2.0*j3+1.0) * dfact(j3+j1-j2)*dfact(j3-j1+j2)*dfact(j1+j2-j3)/dfact(j1+j2+j3+1));
  pre *= sqrt(dfact(j3+m3)*dfact(j3-m3)*dfact(j1-m1)*dfact(j1+m1)*dfact(j2-m2)*dfact(j2+m2));
  double s=0.0;
  for(int k=0;k<=j1+j2+j3;++k){
    int a1=k, a2=j1+j2-j3-k, a3=j1-m1-k, a4=j2+m2-k, a5=j3-j2+m1+k, a6=j3-j1-m2+k;
    if(a1<0||a2<0||a3<0||a4<0||a5<0||a6<0) continue;
    double d = dfact(a1)*dfact(a2)*dfact(a3)*dfact(a4)*dfact(a5)*dfact(a6);
    s += ((k&1)? -1.0:1.0)/d;
  }
  return pre*s;
}

__device__ void fill_u(int l, double* ur, double* ui){
  for(int i=0;i<49;++i){ ur[i]=0.0; ui[i]=0.0; }
  const double s = 0.70710678118654752440;
  for(int m=-l;m<=l;++m){
    if(m==0){ ur[l*7+l]=1.0; }
    else if(m>0){
      ur[(m+l)*7+(m+l)] = ((m&1)? -s : s);
      ur[(m+l)*7+(l-m)] = s;
    } else {
      int a=-m;
      ui[(m+l)*7+(m+l)] = s;               //  1j*s
      ui[(m+l)*7+(a+l)] = ((a&1)? s : -s); // -1j*(-1)^a*s
    }
  }
}

// one block per path; duplicate keys write identical values (benign)
__global__ void init_cg_kernel(float* __restrict__ cg){
  const PathC pc = c_paths.p[blockIdx.x];
  const int l1=pc.li, l2=pc.lf, l3=pc.lo;
  __shared__ double u1r[49],u1i[49],u2r[49],u2i[49],u3r[49],u3i[49];
  __shared__ double s_tr[343], s_ti[343];
  __shared__ int s_flag;
  if(threadIdx.x==0){ fill_u(l1,u1r,u1i); fill_u(l2,u2r,u2i); fill_u(l3,u3r,u3i); }
  __syncthreads();
  const int d1=2*l1+1,d2=2*l2+1,d3=2*l3+1, ne=d1*d2*d3;
  for(int e=threadIdx.x;e<ne;e+=blockDim.x){
    int a=e/(d2*d3); int r=e-a*d2*d3; int bq=r/d3; int c=r-bq*d3;
    double Tr=0.0, Ti=0.0;
    for(int ic=0;ic<d1;++ic){
      double ar=u1r[a*7+ic], ai=u1i[a*7+ic];
      if(ar==0.0 && ai==0.0) continue;
      for(int jc=0;jc<d2;++jc){
        double br=u2r[bq*7+jc], bi=u2i[bq*7+jc];
        if(br==0.0 && bi==0.0) continue;
        int m1=ic-l1, m2=jc-l2, m3=m1+m2;
        if(m3<-l3||m3>l3) continue;
        int kc=m3+l3;
        double cr=u3r[c*7+kc], ci=-u3i[c*7+kc];
        double cgv=cg_coef(l1,m1,l2,m2,l3,m3);
        double abr=ar*br-ai*bi, abi=ar*bi+ai*br;
        Tr += (abr*cr-abi*ci)*cgv;
        Ti += (abr*ci+abi*cr)*cgv;
      }
    }
    s_tr[e]=Tr; s_ti[e]=Ti;
  }
  __syncthreads();
  if(threadIdx.x==0){
    double sr=0.0, si=0.0;
    for(int e=0;e<ne;++e){ sr+=fabs(s_tr[e]); si+=fabs(s_ti[e]); }
    s_flag = (sr>=si)?1:0;
  }
  __syncthreads();
  const int keybase = ((l1*4+l2)*4+l3)*343;
  for(int e=threadIdx.x;e<ne;e+=blockDim.x){
    int a=e/(d2*d3); int r=e-a*d2*d3; int f=r/d3; int o=r-f*d3;
    cg[keybase + (a*7+f)*7 + o] = (float)(s_flag? s_tr[e] : s_ti[e]);
  }
}

// ---------------- unrolled A·Q contraction ----------------
template<int DLI,int DLF>
__device__ __forceinline__ float dotAQ(const float* __restrict__ A, const float* __restrict__ Q,
                                       int CIN, int dlo){
  float s=0.f;
  #pragma unroll
  for(int i=0;i<DLI;++i){
    #pragma unroll
    for(int f=0;f<DLF;++f){
      s += A[f*CIN+i] * Q[(i*DLF+f)*dlo];
    }
  }
  return s;
}

// ---------------- per-layer kernel ----------------
template<int L>
__global__ __launch_bounds__(256) void layer_kernel(
    const float* __restrict__ fin, const int* __restrict__ z, const float* __restrict__ table,
    const float* __restrict__ pos, const float* __restrict__ maskp,
    const float* __restrict__ rw, const float* __restrict__ cg, float* __restrict__ fout)
{
  constexpr int C_IN = (L==0)?32:128;
  constexpr int PBEG = (L==0)?0:(L==1?4:38);
  constexpr int NP   = (L==0)?4:34;
  constexpr int NQ   = (L==0)?84:3436;
  constexpr int NT   = (L==0)?512:1460;
  constexpr int NO   = (L==0)?152:1236;
  constexpr int NI_T = (NT+255)/256;
  constexpr int NI_O = (NO+255)/256;

  __shared__ __align__(16) float s_fin[NA*C_IN];
  __shared__ __align__(16) float s_A[16*C_IN];
  __shared__ float s_Y[NA*16];
  __shared__ float s_rb[NA*10];
  __shared__ float s_T[NT];
  __shared__ float s_Q[NQ];
  __shared__ float s_out[C_OUT];
  __shared__ float s_gate[24];
  __shared__ int   s_meta[NP*2];

  const int tid = threadIdx.x;
  const int b = blockIdx.x / NA, a = blockIdx.x % NA;

  const unsigned short* QT = (L==0)? c_it.q0  : c_it.q12;
  const unsigned short* TT = (L==0)? c_it.t0  : c_it.t12;
  const unsigned short* OT = (L==0)? c_it.o0  : c_it.o12;

  // ---- block-start staging ----
  if(tid < C_OUT) s_out[tid] = 0.f;

  // pair data (Y, masked rbasis) for this center atom a
  if(tid < NA){
    const int j = tid;
    const float* pa = pos + (b*NA+a)*3;
    const float* pj = pos + (b*NA+j)*3;
    float dx=pj[0]-pa[0], dy=pj[1]-pa[1], dz=pj[2]-pa[2];
    float r = sqrtf(dx*dx+dy*dy+dz*dz + 1e-12f);
    float inv = 1.f/(r + 1e-9f);
    float x=dx*inv, y=dy*inv, zz=dz*inv;
    float r2 = x*x+y*y+zz*zz;
    float* Yp = s_Y + j*16;
    Yp[0] = 0.28209479177387814f;
    Yp[1] = 0.4886025119029199f*y;
    Yp[2] = 0.4886025119029199f*zz;
    Yp[3] = 0.4886025119029199f*x;
    Yp[4] = 1.0925484305920792f*x*y;
    Yp[5] = 1.0925484305920792f*y*zz;
    Yp[6] = 0.31539156525252005f*(3.f*zz*zz - r2);
    Yp[7] = 1.0925484305920792f*x*zz;
    Yp[8] = 0.5462742152960396f*(x*x - y*y);
    Yp[9] = 0.5900435899266435f*y*(3.f*x*x - y*y);
    Yp[10]= 2.890611442640554f*x*y*zz;
    Yp[11]= 0.4570457994644658f*y*(5.f*zz*zz - r2);
    Yp[12]= 0.3731763325901154f*zz*(5.f*zz*zz - 3.f*r2);
    Yp[13]= 0.4570457994644658f*x*(5.f*zz*zz - r2);
    Yp[14]= 1.445305721320277f*zz*(x*x - y*y);
    Yp[15]= 0.5900435899266435f*x*(x*x - 3.f*y*y);
    float mk = maskp[b*NA+j];
    const float w = 5.f/9.f;
    for(int k=0;k<10;++k){
      float ck = 5.f*(float)k/9.f;
      float tt = (r-ck)/w;
      s_rb[j*10+k] = expf(-0.5f*tt*tt)*mk;
    }
  }

  // input features
  if(L==0){
    for(int i=tid;i<NA*EMBED;i+=256){
      int j = i>>5, c = i&31;
      s_fin[i] = table[z[b*NA+j]*EMBED + c];
    }
  } else {
    const float4* fg = reinterpret_cast<const float4*>(fin + b*NA*C_IN);
    float4* fs = reinterpret_cast<float4*>(s_fin);
    #pragma unroll
    for(int r=0;r<(NA*C_IN/4+255)/256;++r){
      int i = tid + r*256;
      if(i < NA*C_IN/4) fs[i] = fg[i];
    }
  }

  // path meta -> LDS
  if(tid < NP){
    const PathC pc = c_paths.p[tid+PBEG];
    int dli=2*pc.li+1, dlf=2*pc.lf+1, dlo=2*pc.lo+1;
    s_meta[tid*2]   = dli | (dlf<<3) | (dlo<<6) | ((pc.lf*pc.lf)<<9) | (pc.ci0<<13);
    s_meta[tid*2+1] = pc.qoff | (pc.toff<<12);
  }

  // CG -> LDS (compact per-layer layout)
  for(int r=tid;r<NQ;r+=256){
    unsigned e = QT[r];
    int prel=e>>9, i=(e>>6)&7, f=(e>>3)&7, o=e&7;
    const PathC pc = c_paths.p[prel+PBEG];
    int dlf=2*pc.lf+1, dlo=2*pc.lo+1;
    s_Q[pc.qoff + (i*dlf+f)*dlo + o] =
        cg[(((pc.li*4+pc.lf)*4+pc.lo)*343) + (i*7+f)*7 + o];
  }

  // out-item register decode
  int wb[NI_O], tb[NI_O], momi[NI_O], mi_r[NI_O], dlo_r[NI_O];
  float acc[NI_O];
  #pragma unroll
  for(int r=0;r<NI_O;++r){
    acc[r]=0.f; wb[r]=-1; tb[r]=0; momi[r]=0; mi_r[r]=0; dlo_r[r]=1;
    int idx = tid + r*256;
    if(idx < NO){
      unsigned e = OT[idx];
      int prel=e>>9, u=(e>>3)&63, o=e&7;
      const PathC pc = c_paths.p[prel+PBEG];
      mi_r[r]=pc.mi; dlo_r[r]=2*pc.lo+1; momi[r]=pc.mo*pc.mi;
      wb[r]=pc.woff + u*pc.mi; tb[r]=pc.toff + o;
    }
  }

  __syncthreads();

  const float4* fs4 = reinterpret_cast<const float4*>(s_fin);
  float4* sA4 = reinterpret_cast<float4*>(s_A);

  // ---- k pipeline ----
  for(int k=0;k<10;++k){
    // stage A: A_k[f][ci] = sum_j rb[j,k]*Y[j,f]*fin[j,ci]
    if(L==0){
      if(tid < 128){
        int f = tid>>3, c4 = tid&7;
        float4 s0 = {0.f,0.f,0.f,0.f};
        #pragma unroll
        for(int j=0;j<NA;++j){
          float ry = s_rb[j*10+k]*s_Y[j*16+f];
          float4 v = fs4[j*8 + c4];
          s0.x += ry*v.x; s0.y += ry*v.y; s0.z += ry*v.z; s0.w += ry*v.w;
        }
        sA4[f*8 + c4] = s0;
      }
    } else {
      int f0 = tid>>5, c4 = tid&31;
      float4 s0 = {0.f,0.f,0.f,0.f}, s1 = {0.f,0.f,0.f,0.f};
      #pragma unroll
      for(int j=0;j<NA;++j){
        float rbv = s_rb[j*10+k];
        float a0 = rbv*s_Y[j*16+f0];
        float a1 = rbv*s_Y[j*16+f0+8];
        float4 v = fs4[j*32 + c4];
        s0.x += a0*v.x; s0.y += a0*v.y; s0.z += a0*v.z; s0.w += a0*v.w;
        s1.x += a1*v.x; s1.y += a1*v.y; s1.z += a1*v.z; s1.w += a1*v.w;
      }
      sA4[f0*32 + c4] = s0;
      sA4[(f0+8)*32 + c4] = s1;
    }
    __syncthreads();

    // stage T: T[p][v][o] = sum_{f,i} A_k[foff+f][ci0+v*dli+i] * Q[p][(i,f),o]
    #pragma unroll
    for(int r=0;r<NI_T;++r){
      int idx = tid + r*256;
      if(idx < NT){
        unsigned e = TT[idx];
        int prel=e>>8, vv=(e>>3)&31, o=e&7;
        int m0 = s_meta[prel*2], m1 = s_meta[prel*2+1];
        int dli=m0&7, dlf=(m0>>3)&7, dlo=(m0>>6)&7, foff=(m0>>9)&15, ci0=(m0>>13);
        int qoff = m1&4095, toff = m1>>12;
        const float* Ab = &s_A[foff*C_IN + ci0 + vv*dli];
        const float* Qb = &s_Q[qoff + o];
        float s = 0.f;
        switch((dli<<4)|dlf){
          case (1<<4)|1: s=dotAQ<1,1>(Ab,Qb,C_IN,dlo); break;
          case (1<<4)|3: s=dotAQ<1,3>(Ab,Qb,C_IN,dlo); break;
          case (1<<4)|5: s=dotAQ<1,5>(Ab,Qb,C_IN,dlo); break;
          case (1<<4)|7: s=dotAQ<1,7>(Ab,Qb,C_IN,dlo); break;
          case (3<<4)|1: s=dotAQ<3,1>(Ab,Qb,C_IN,dlo); break;
          case (3<<4)|3: s=dotAQ<3,3>(Ab,Qb,C_IN,dlo); break;
          case (3<<4)|5: s=dotAQ<3,5>(Ab,Qb,C_IN,dlo); break;
          case (3<<4)|7: s=dotAQ<3,7>(Ab,Qb,C_IN,dlo); break;
          case (5<<4)|1: s=dotAQ<5,1>(Ab,Qb,C_IN,dlo); break;
          case (5<<4)|3: s=dotAQ<5,3>(Ab,Qb,C_IN,dlo); break;
          case (5<<4)|5: s=dotAQ<5,5>(Ab,Qb,C_IN,dlo); break;
          case (5<<4)|7: s=dotAQ<5,7>(Ab,Qb,C_IN,dlo); break;
          case (7<<4)|1: s=dotAQ<7,1>(Ab,Qb,C_IN,dlo); break;
          case (7<<4)|3: s=dotAQ<7,3>(Ab,Qb,C_IN,dlo); break;
          case (7<<4)|5: s=dotAQ<7,5>(Ab,Qb,C_IN,dlo); break;
          case (7<<4)|7: s=dotAQ<7,7>(Ab,Qb,C_IN,dlo); break;
          default: break;
        }
        s_T[toff + vv*dlo + o] = s;
      }
    }
    __syncthreads();

    // stage out: acc += sum_v W[k,u,v] * T[v,o]
    #pragma unroll
    for(int r=0;r<NI_O;++r){
      if(wb[r] >= 0){
        const float4* Wp = reinterpret_cast<const float4*>(rw + wb[r] + k*momi[r]);
        const int d = dlo_r[r];
        int t = tb[r];
        float s = 0.f;
        for(int v4=0; v4<(mi_r[r]>>2); ++v4){
          float4 w = Wp[v4];
          s += w.x*s_T[t] + w.y*s_T[t+d] + w.z*s_T[t+2*d] + w.w*s_T[t+3*d];
          t += 4*d;
        }
        acc[r] += s;
      }
    }
    __syncthreads();
  }

  // ---- reduce path contributions ----
  #pragma unroll
  for(int r=0;r<NI_O;++r){
    if(wb[r] >= 0){
      int idx = tid + r*256;
      unsigned e = OT[idx];
      int prel=e>>9, u=(e>>3)&63, o=e&7;
      const PathC pc = c_paths.p[prel+PBEG];
      atomicAdd(&s_out[pc.obase + u*(2*pc.lo+1) + o], acc[r]*pc.scale);
    }
  }
  __syncthreads();

  // ---- gated epilogue ----
  if(tid < 24) s_gate[tid] = 1.f/(1.f+expf(-s_out[24+tid]));
  __syncthreads();
  const float mval = maskp[b*NA+a];
  for(int c=tid;c<C_FEAT;c+=256){
    float val;
    if(c<24)       { val = fmaxf(s_out[c], 0.f); }
    else if(c<60)  { int r=c-24;  int v=r/3; val = s_out[48+r]  * s_gate[v]; }
    else if(c<100) { int r=c-60;  int v=r/5; val = s_out[84+r]  * s_gate[12+v]; }
    else           { int r=c-100; int v=r/7; val = s_out[124+r] * s_gate[20+v]; }
    fout[(b*NA+a)*C_FEAT + c] = val*mval;
  }
}

// ---------------- launch ----------------
extern "C" void kernel_launch(void* const* d_in, const int* in_sizes, int n_in,
                              void* d_out, int out_size, void* d_ws, size_t ws_size,
                              hipStream_t stream) {
  const int*   z     = (const int*)  d_in[0];
  const float* pos   = (const float*)d_in[1];
  const float* mask  = (const float*)d_in[2];
  const float* table = (const float*)d_in[3];
  const float* rw    = (const float*)d_in[4];
  float* out = (float*)d_out;
  float* ws  = (float*)d_ws;

  float* cg  = ws;                 // 64*343 = 21952 floats
  float* fA  = cg  + 21952;        // 32*24*128 = 98304
  float* fB  = fA  + 98304;        // 32*24*128 = 98304

  init_cg_kernel<<<72, 384, 0, stream>>>(cg);

  layer_kernel<0><<<NB*NA, 256, 0, stream>>>(nullptr, z, table, pos, mask, rw, cg, fA);
  layer_kernel<1><<<NB*NA, 256, 0, stream>>>(fA, z, table, pos, mask, rw, cg, fB);
  layer_kernel<2><<<NB*NA, 256, 0, stream>>>(fB, z, table, pos, mask, rw, cg, out);
}

// Round 3
// 484.997 us; speedup vs baseline: 13.8584x; 1.2134x over previous
//
#include <hip/hip_runtime.h>
#include <math.h>

// ---------------- problem constants ----------------
#define NB 32      // molecules
#define NA 24      // atoms
#define EMBED 32
#define C_FEAT 128 // 24 + 12*3 + 8*5 + 4*7
#define C_OUT 152  // 48 + 12*3 + 8*5 + 4*7

// ---------------- constexpr path table ----------------
struct PathC { int li, mi, lo, mo, lf, woff, toff, ci0, obase, sqoff, pobase; float scale; };
struct PTable { PathC p[72]; };

constexpr double csqrt_(double x){ double g = x < 1.0 ? 1.0 : x; for(int i=0;i<80;++i) g = 0.5*(g + x/g); return g; }

constexpr PTable build_paths(){
  PTable t{};
  int off=0, n=0;
  for(int layer=0; layer<3; ++layer){
    int toff=0, sqoff=0, pobase=0;
    const int nin = (layer==0)?1:4;
    for(int ii=0; ii<nin; ++ii){
      const int mi_a[4]={24,12,8,4};
      const int ci0_a[4]={0,24,60,100};
      const int mi = (layer==0)?32:mi_a[ii];
      const int li = (layer==0)?0:ii;
      const int ci0 = (layer==0)?0:ci0_a[ii];
      const int mo_a[4]={48,12,8,4};
      const int ob_a[4]={0,48,84,124};
      for(int oo=0; oo<4; ++oo){
        int mo=mo_a[oo], lo=oo;
        int lfmin = li>lo? li-lo : lo-li;
        int lfmax = (li+lo)<3 ? (li+lo) : 3;
        for(int lf=lfmin; lf<=lfmax; ++lf){
          int dli=2*li+1, dlf=2*lf+1, dlo=2*lo+1;
          t.p[n].li=li; t.p[n].mi=mi; t.p[n].lo=lo; t.p[n].mo=mo; t.p[n].lf=lf;
          t.p[n].woff=off; t.p[n].toff=toff; t.p[n].ci0=ci0; t.p[n].obase=ob_a[lo];
          t.p[n].sqoff=sqoff; t.p[n].pobase=pobase;
          t.p[n].scale=(float)(1.0/(csqrt_(10.0*mi)*csqrt_(18.0)));
          off += 10*mo*mi;
          toff += mi*dlo;
          sqoff += 2*dli*dlf;
          pobase += dlo;
          ++n;
        }
      }
    }
  }
  return t;
}
constexpr int total_woff(){
  PTable t = build_paths();
  return t.p[71].woff + 10*t.p[71].mo*t.p[71].mi;
}
static_assert(total_woff()==114880, "weight offset mismatch");
constexpr PTable g_pt_chk = build_paths();
static_assert(g_pt_chk.p[37].sqoff + 2*7*7 == 1476, "L12 sq cap");
static_assert(g_pt_chk.p[3].sqoff  + 2*1*7 == 32,   "L0 sq cap");
static_assert(g_pt_chk.p[37].pobase + 7 == 156, "L12 po count");
static_assert(g_pt_chk.p[37].toff + 4*7 == 1460, "L12 T size");
static_assert(g_pt_chk.p[3].toff + 32*7 == 512, "L0 T size");
__constant__ PTable c_paths = build_paths();

#define SQCAP_L0 32
#define SQCAP_L12 1476
#define NPO_L0 16
#define NPO_L12 156

// ---------------- constexpr work-item tables ----------------
// t-items (u32): waddr(11) | base(7)<<11 | poIdx(8)<<18
// o-items (u16): prel<<9 | u<<3 | o
struct ITables {
  unsigned t0[512]; unsigned t12[1460];
  unsigned short o0[152]; unsigned short o12[1236];
  int nt0, no0, nt12, no12;
};
constexpr ITables build_items(){
  ITables it{};
  PTable pt = build_paths();
  {
    int nt=0,no=0;
    for(int p=0;p<4;++p){
      const PathC pc = pt.p[p];
      int dli=2*pc.li+1, dlo=2*pc.lo+1;
      for(int v=0;v<pc.mi;++v)for(int o=0;o<dlo;++o){
        unsigned waddr = (unsigned)(pc.toff + o*pc.mi + v);
        unsigned base  = (unsigned)(pc.ci0 + v*dli);
        unsigned po    = (unsigned)(pc.pobase + o);
        it.t0[nt++] = waddr | (base<<11) | (po<<18);
      }
      for(int u=0;u<pc.mo;++u)for(int o=0;o<dlo;++o)
        it.o0[no++]=(unsigned short)((p<<9)|(u<<3)|o);
    }
    it.nt0=nt; it.no0=no;
  }
  {
    int nt=0,no=0;
    for(int p=4;p<38;++p){
      const PathC pc = pt.p[p];
      int prel = p-4;
      int dli=2*pc.li+1, dlo=2*pc.lo+1;
      for(int v=0;v<pc.mi;++v)for(int o=0;o<dlo;++o){
        unsigned waddr = (unsigned)(pc.toff + o*pc.mi + v);
        unsigned base  = (unsigned)(pc.ci0 + v*dli);
        unsigned po    = (unsigned)(pc.pobase + o);
        it.t12[nt++] = waddr | (base<<11) | (po<<18);
      }
      for(int u=0;u<pc.mo;++u)for(int o=0;o<dlo;++o)
        it.o12[no++]=(unsigned short)((prel<<9)|(u<<3)|o);
    }
    it.nt12=nt; it.no12=no;
  }
  return it;
}
constexpr ITables g_it_chk = build_items();
static_assert(g_it_chk.nt0==512 && g_it_chk.no0==152, "l0 counts");
static_assert(g_it_chk.nt12==1460 && g_it_chk.no12==1236, "l12 counts");
__constant__ ITables c_it = build_items();

// ---------------- CG init + sparse compaction (fp64, every launch) ----------------
__device__ double dfact(int n){ double r=1.0; for(int i=2;i<=n;++i) r*=(double)i; return r; }

__device__ double cg_coef(int j1,int m1,int j2,int m2,int j3,int m3){
  if (m1+m2 != m3) return 0.0;
  double pre = sqrt((2.0*j3+1.0) * dfact(j3+j1-j2)*dfact(j3-j1+j2)*dfact(j1+j2-j3)/dfact(j1+j2+j3+1));
  pre *= sqrt(dfact(j3+m3)*dfact(j3-m3)*dfact(j1-m1)*dfact(j1+m1)*dfact(j2-m2)*dfact(j2+m2));
  double s=0.0;
  for(int k=0;k<=j1+j2+j3;++k){
    int a1=k, a2=j1+j2-j3-k, a3=j1-m1-k, a4=j2+m2-k, a5=j3-j2+m1+k, a6=j3-j1-m2+k;
    if(a1<0||a2<0||a3<0||a4<0||a5<0||a6<0) continue;
    double d = dfact(a1)*dfact(a2)*dfact(a3)*dfact(a4)*dfact(a5)*dfact(a6);
    s += ((k&1)? -1.0:1.0)/d;
  }
  return pre*s;
}

__device__ void fill_u(int l, double* ur, double* ui){
  for(int i=0;i<49;++i){ ur[i]=0.0; ui[i]=0.0; }
  const double s = 0.70710678118654752440;
  for(int m=-l;m<=l;++m){
    if(m==0){ ur[l*7+l]=1.0; }
    else if(m>0){
      ur[(m+l)*7+(m+l)] = ((m&1)? -s : s);
      ur[(m+l)*7+(l-m)] = s;
    } else {
      int a=-m;
      ui[(m+l)*7+(m+l)] = s;               //  1j*s
      ui[(m+l)*7+(a+l)] = ((a&1)? s : -s); // -1j*(-1)^a*s
    }
  }
}

// one block per path (0..37); writes compact sparse lists + per-(path,o) meta
__global__ void init_cg_kernel(float2* __restrict__ sq, unsigned* __restrict__ meta){
  const int p = blockIdx.x;
  const PathC pc = c_paths.p[p];
  const int l1=pc.li, l2=pc.lf, l3=pc.lo;
  __shared__ double u1r[49],u1i[49],u2r[49],u2i[49],u3r[49],u3i[49];
  __shared__ double s_tr[343], s_ti[343];
  __shared__ int s_flag;
  if(threadIdx.x==0){ fill_u(l1,u1r,u1i); fill_u(l2,u2r,u2i); fill_u(l3,u3r,u3i); }
  __syncthreads();
  const int d1=2*l1+1,d2=2*l2+1,d3=2*l3+1, ne=d1*d2*d3;
  for(int e=threadIdx.x;e<ne;e+=blockDim.x){
    int a=e/(d2*d3); int r=e-a*d2*d3; int bq=r/d3; int c=r-bq*d3;
    double Tr=0.0, Ti=0.0;
    for(int ic=0;ic<d1;++ic){
      double ar=u1r[a*7+ic], ai=u1i[a*7+ic];
      if(ar==0.0 && ai==0.0) continue;
      for(int jc=0;jc<d2;++jc){
        double br=u2r[bq*7+jc], bi=u2i[bq*7+jc];
        if(br==0.0 && bi==0.0) continue;
        int m1=ic-l1, m2=jc-l2, m3=m1+m2;
        if(m3<-l3||m3>l3) continue;
        int kc=m3+l3;
        double cr=u3r[c*7+kc], ci=-u3i[c*7+kc];
        double cgv=cg_coef(l1,m1,l2,m2,l3,m3);
        double abr=ar*br-ai*bi, abi=ar*bi+ai*br;
        Tr += (abr*cr-abi*ci)*cgv;
        Ti += (abr*ci+abi*cr)*cgv;
      }
    }
    s_tr[e]=Tr; s_ti[e]=Ti;
  }
  __syncthreads();
  if(threadIdx.x==0){
    double sr=0.0, si=0.0;
    for(int e=0;e<ne;++e){ sr+=fabs(s_tr[e]); si+=fabs(s_ti[e]); }
    s_flag = (sr>=si)?1:0;
  }
  __syncthreads();
  if(threadIdx.x==0){
    const int C_IN_l = (p<4)?32:128;
    const int sqAbs  = (p<4)?0:SQCAP_L0;     // region base in entries
    const int mAbs   = (p<4)?0:NPO_L0;       // region base in metas
    const int foff   = pc.lf*pc.lf;
    const int cap    = 2*d1*d2;
    int cnt = pc.sqoff;                      // region-relative running offset
    for(int o=0;o<d3;++o){
      int start = cnt;
      for(int i=0;i<d1;++i) for(int f=0;f<d2;++f){
        double val = s_flag ? s_tr[(i*d2+f)*d3+o] : s_ti[(i*d2+f)*d3+o];
        if(fabs(val) > 1e-12 && (cnt - pc.sqoff) < cap){
          float2 e2; e2.x=(float)val; e2.y=__uint_as_float((unsigned)((foff+f)*C_IN_l + i));
          sq[sqAbs + cnt] = e2;
          ++cnt;
        }
      }
      meta[mAbs + pc.pobase + o] = (unsigned)start | ((unsigned)(cnt-start)<<16);
    }
  }
}

// ---------------- per-layer kernel ----------------
template<int L>
__global__ __launch_bounds__(256) void layer_kernel(
    const float* __restrict__ fin, const int* __restrict__ z, const float* __restrict__ table,
    const float* __restrict__ pos, const float* __restrict__ maskp,
    const float* __restrict__ rw, const float2* __restrict__ sqg,
    const unsigned* __restrict__ metag, float* __restrict__ fout)
{
  constexpr int C_IN  = (L==0)?32:128;
  constexpr int PBEG  = (L==0)?0:(L==1?4:38);
  constexpr int NT    = (L==0)?512:1460;
  constexpr int NO    = (L==0)?152:1236;
  constexpr int SQCAP = (L==0)?SQCAP_L0:SQCAP_L12;
  constexpr int NPO   = (L==0)?NPO_L0:NPO_L12;
  constexpr int SQB   = (L==0)?0:SQCAP_L0;
  constexpr int MB    = (L==0)?0:NPO_L0;
  constexpr int NI_T  = (NT+255)/256;
  constexpr int NI_O  = (NO+255)/256;

  __shared__ __align__(16) float s_fin[NA*C_IN];
  __shared__ __align__(16) float s_A[16*C_IN];
  __shared__ __align__(16) float s_T[NT];
  __shared__ float          s_sqc[SQCAP];
  __shared__ unsigned short s_sqi[SQCAP];
  __shared__ unsigned s_po[NPO];
  __shared__ float s_Y[NA*16];
  __shared__ float s_rb[NA*10];
  __shared__ float s_out[C_OUT];
  __shared__ float s_gate[24];

  const int tid = threadIdx.x;
  const int b = blockIdx.x / NA, a = blockIdx.x % NA;

  const unsigned*       TT = (L==0)? c_it.t0 : c_it.t12;
  const unsigned short* OT = (L==0)? c_it.o0 : c_it.o12;

  // ---- prologue ----
  if(tid < C_OUT) s_out[tid] = 0.f;

  if(tid < NA){
    const int j = tid;
    const float* pa = pos + (b*NA+a)*3;
    const float* pj = pos + (b*NA+j)*3;
    float dx=pj[0]-pa[0], dy=pj[1]-pa[1], dz=pj[2]-pa[2];
    float r = sqrtf(dx*dx+dy*dy+dz*dz + 1e-12f);
    float inv = 1.f/(r + 1e-9f);
    float x=dx*inv, y=dy*inv, zz=dz*inv;
    float r2 = x*x+y*y+zz*zz;
    float* Yp = s_Y + j*16;
    Yp[0] = 0.28209479177387814f;
    Yp[1] = 0.4886025119029199f*y;
    Yp[2] = 0.4886025119029199f*zz;
    Yp[3] = 0.4886025119029199f*x;
    Yp[4] = 1.0925484305920792f*x*y;
    Yp[5] = 1.0925484305920792f*y*zz;
    Yp[6] = 0.31539156525252005f*(3.f*zz*zz - r2);
    Yp[7] = 1.0925484305920792f*x*zz;
    Yp[8] = 0.5462742152960396f*(x*x - y*y);
    Yp[9] = 0.5900435899266435f*y*(3.f*x*x - y*y);
    Yp[10]= 2.890611442640554f*x*y*zz;
    Yp[11]= 0.4570457994644658f*y*(5.f*zz*zz - r2);
    Yp[12]= 0.3731763325901154f*zz*(5.f*zz*zz - 3.f*r2);
    Yp[13]= 0.4570457994644658f*x*(5.f*zz*zz - r2);
    Yp[14]= 1.445305721320277f*zz*(x*x - y*y);
    Yp[15]= 0.5900435899266435f*x*(x*x - 3.f*y*y);
    float mk = maskp[b*NA+j];
    const float w = 5.f/9.f;
    for(int k=0;k<10;++k){
      float ck = 5.f*(float)k/9.f;
      float tt = (r-ck)/w;
      s_rb[j*10+k] = expf(-0.5f*tt*tt)*mk;
    }
  }

  if(L==0){
    for(int i=tid;i<NA*EMBED;i+=256){
      int j = i>>5, c = i&31;
      s_fin[i] = table[z[b*NA+j]*EMBED + c];
    }
  } else {
    const float4* fg = reinterpret_cast<const float4*>(fin + b*NA*C_IN);
    float4* fs = reinterpret_cast<float4*>(s_fin);
    #pragma unroll
    for(int r=0;r<(NA*C_IN/4+255)/256;++r){
      int i = tid + r*256;
      if(i < NA*C_IN/4) fs[i] = fg[i];
    }
  }

  // sparse CG -> LDS (split coef/idx)
  for(int i=tid;i<SQCAP;i+=256){
    float2 e2 = sqg[SQB+i];
    s_sqc[i] = e2.x;
    s_sqi[i] = (unsigned short)__float_as_uint(e2.y);
  }
  if(tid < NPO) s_po[tid] = metag[MB+tid];

  // out-item register decode
  int wb[NI_O], momi[NI_O], mi4_[NI_O], t4b[NI_O];
  float acc[NI_O];
  #pragma unroll
  for(int r=0;r<NI_O;++r){
    acc[r]=0.f; wb[r]=-1; momi[r]=0; mi4_[r]=0; t4b[r]=0;
    int idx = tid + r*256;
    if(idx < NO){
      unsigned e = OT[idx];
      int prel=e>>9, u=(e>>3)&63, o=e&7;
      const PathC pc = c_paths.p[prel+PBEG];
      wb[r]=pc.woff + u*pc.mi; momi[r]=pc.mo*pc.mi; mi4_[r]=pc.mi>>2;
      t4b[r]=(pc.toff + o*pc.mi)>>2;
    }
  }

  const float4* fs4 = reinterpret_cast<const float4*>(s_fin);
  float4* sA4 = reinterpret_cast<float4*>(s_A);

  // stage A: A_k[f][ci] = sum_j rb[j,k]*Y[j,f]*fin[j,ci]; 128 threads, parity-alternating half
  auto stageA = [&](int k){
    bool active = (k&1) ? (tid>=128) : (tid<128);
    if(!active) return;
    const int g = tid & 127;
    if(L==0){
      int f = g>>3, c4 = g&7;
      float4 s0 = {0.f,0.f,0.f,0.f};
      #pragma unroll
      for(int j=0;j<NA;++j){
        float ry = s_rb[j*10+k]*s_Y[j*16+f];
        float4 v = fs4[j*8 + c4];
        s0.x += ry*v.x; s0.y += ry*v.y; s0.z += ry*v.z; s0.w += ry*v.w;
      }
      sA4[f*8 + c4] = s0;
    } else {
      int f0 = g>>5, c4 = g&31;     // rows f0, f0+4, f0+8, f0+12
      float4 a0={0,0,0,0}, a1={0,0,0,0}, a2={0,0,0,0}, a3={0,0,0,0};
      #pragma unroll
      for(int j=0;j<NA;++j){
        float rbv = s_rb[j*10+k];
        float y0 = rbv*s_Y[j*16+f0];
        float y1 = rbv*s_Y[j*16+f0+4];
        float y2 = rbv*s_Y[j*16+f0+8];
        float y3 = rbv*s_Y[j*16+f0+12];
        float4 v = fs4[j*32 + c4];
        a0.x += y0*v.x; a0.y += y0*v.y; a0.z += y0*v.z; a0.w += y0*v.w;
        a1.x += y1*v.x; a1.y += y1*v.y; a1.z += y1*v.z; a1.w += y1*v.w;
        a2.x += y2*v.x; a2.y += y2*v.y; a2.z += y2*v.z; a2.w += y2*v.w;
        a3.x += y3*v.x; a3.y += y3*v.y; a3.z += y3*v.z; a3.w += y3*v.w;
      }
      sA4[(f0   )*32 + c4] = a0;
      sA4[(f0+ 4)*32 + c4] = a1;
      sA4[(f0+ 8)*32 + c4] = a2;
      sA4[(f0+12)*32 + c4] = a3;
    }
  };

  __syncthreads();
  stageA(0);
  __syncthreads();

  // ---- k pipeline: [T(k)] bar [out(k) + A(k+1)] bar ----
  for(int k=0;k<10;++k){
    // stage T (sparse): T[waddr] = sum_nnz coef * A[idx + base]
    #pragma unroll
    for(int r=0;r<NI_T;++r){
      int idx = tid + r*256;
      if(idx < NT){
        unsigned e = TT[idx];
        int waddr = e & 2047;
        int base  = (e>>11)&127;
        unsigned m = s_po[(e>>18)&255];
        int off = m & 0xffff, len = (int)(m>>16);
        float s = 0.f;
        for(int n=0;n<len;++n){
          s += s_sqc[off+n] * s_A[(int)s_sqi[off+n] + base];
        }
        s_T[waddr] = s;
      }
    }
    __syncthreads();

    // stage out: acc += sum_v W[k,u,v] * T[o][v]   (float4 both sides)
    #pragma unroll
    for(int r=0;r<NI_O;++r){
      if(wb[r] >= 0){
        const float4* Wp = reinterpret_cast<const float4*>(rw + wb[r] + k*momi[r]);
        const float4* Tp = reinterpret_cast<const float4*>(s_T) + t4b[r];
        float s = 0.f;
        for(int v4=0; v4<mi4_[r]; ++v4){
          float4 w = Wp[v4], t = Tp[v4];
          s += w.x*t.x + w.y*t.y + w.z*t.z + w.w*t.w;
        }
        acc[r] += s;
      }
    }
    if(k<9) stageA(k+1);
    __syncthreads();
  }

  // ---- reduce path contributions ----
  #pragma unroll
  for(int r=0;r<NI_O;++r){
    if(wb[r] >= 0){
      int idx = tid + r*256;
      unsigned e = OT[idx];
      int prel=e>>9, u=(e>>3)&63, o=e&7;
      const PathC pc = c_paths.p[prel+PBEG];
      atomicAdd(&s_out[pc.obase + u*(2*pc.lo+1) + o], acc[r]*pc.scale);
    }
  }
  __syncthreads();

  // ---- gated epilogue ----
  if(tid < 24) s_gate[tid] = 1.f/(1.f+expf(-s_out[24+tid]));
  __syncthreads();
  const float mval = maskp[b*NA+a];
  for(int c=tid;c<C_FEAT;c+=256){
    float val;
    if(c<24)       { val = fmaxf(s_out[c], 0.f); }
    else if(c<60)  { int r=c-24;  int v=r/3; val = s_out[48+r]  * s_gate[v]; }
    else if(c<100) { int r=c-60;  int v=r/5; val = s_out[84+r]  * s_gate[12+v]; }
    else           { int r=c-100; int v=r/7; val = s_out[124+r] * s_gate[20+v]; }
    fout[(b*NA+a)*C_FEAT + c] = val*mval;
  }
}

// ---------------- launch ----------------
extern "C" void kernel_launch(void* const* d_in, const int* in_sizes, int n_in,
                              void* d_out, int out_size, void* d_ws, size_t ws_size,
                              hipStream_t stream) {
  const int*   z     = (const int*)  d_in[0];
  const float* pos   = (const float*)d_in[1];
  const float* mask  = (const float*)d_in[2];
  const float* table = (const float*)d_in[3];
  const float* rw    = (const float*)d_in[4];
  float* out = (float*)d_out;
  float* ws  = (float*)d_ws;

  float2*   sq   = (float2*)ws;                 // 1508 entries (32 + 1476) -> 3016 floats
  unsigned* meta = (unsigned*)(ws + 3016);      // 172 u32
  float* fA = ws + 3016 + 172 + 12;             // pad to 3200 (16B-aligned); 32*24*128
  float* fB = fA + 98304;

  init_cg_kernel<<<38, 256, 0, stream>>>(sq, meta);

  layer_kernel<0><<<NB*NA, 256, 0, stream>>>(nullptr, z, table, pos, mask, rw, sq, meta, fA);
  layer_kernel<1><<<NB*NA, 256, 0, stream>>>(fA, z, table, pos, mask, rw, sq, meta, fB);
  layer_kernel<2><<<NB*NA, 256, 0, stream>>>(fB, z, table, pos, mask, rw, sq, meta, out);
}

// Round 4
// 305.911 us; speedup vs baseline: 21.9713x; 1.5854x over previous
//
#include <hip/hip_runtime.h>
#include <math.h>

// ---------------- problem constants ----------------
#define NB 32      // molecules
#define NA 24      // atoms
#define EMBED 32
#define C_FEAT 128 // 24 + 12*3 + 8*5 + 4*7
#define C_OUT 152  // 48 + 12*3 + 8*5 + 4*7

// ---------------- constexpr path table ----------------
struct PathC { int li, mi, lo, mo, lf, woff, toff, ci0, obase, pobase; float scale; };
struct PTable { PathC p[72]; };

constexpr double csqrt_(double x){ double g = x < 1.0 ? 1.0 : x; for(int i=0;i<48;++i) g = 0.5*(g + x/g); return g; }

constexpr PTable build_paths(){
  PTable t{};
  int off=0, n=0;
  for(int layer=0; layer<3; ++layer){
    int toff=0, pobase=0;
    const int nin = (layer==0)?1:4;
    for(int ii=0; ii<nin; ++ii){
      const int mi_a[4]={24,12,8,4};
      const int ci0_a[4]={0,24,60,100};
      const int mi = (layer==0)?32:mi_a[ii];
      const int li = (layer==0)?0:ii;
      const int ci0 = (layer==0)?0:ci0_a[ii];
      const int mo_a[4]={48,12,8,4};
      const int ob_a[4]={0,48,84,124};
      for(int oo=0; oo<4; ++oo){
        int mo=mo_a[oo], lo=oo;
        int lfmin = li>lo? li-lo : lo-li;
        int lfmax = (li+lo)<3 ? (li+lo) : 3;
        for(int lf=lfmin; lf<=lfmax; ++lf){
          int dlo=2*lo+1;
          t.p[n].li=li; t.p[n].mi=mi; t.p[n].lo=lo; t.p[n].mo=mo; t.p[n].lf=lf;
          t.p[n].woff=off; t.p[n].toff=toff; t.p[n].ci0=ci0; t.p[n].obase=ob_a[lo];
          t.p[n].pobase=pobase;
          t.p[n].scale=(float)(1.0/(csqrt_(10.0*mi)*csqrt_(18.0)));
          off += 10*mo*mi;
          toff += mi*dlo;
          pobase += dlo;
          ++n;
        }
      }
    }
  }
  return t;
}
constexpr int total_woff(){
  PTable t = build_paths();
  return t.p[71].woff + 10*t.p[71].mo*t.p[71].mi;
}
static_assert(total_woff()==114880, "weight offset mismatch");
__constant__ PTable c_paths = build_paths();

// ---------------- constexpr real Clebsch-Gordan ----------------
constexpr double cfact_(int n){ double r=1.0; for(int i=2;i<=n;++i) r*=(double)i; return r; }

constexpr double ccg_(int j1,int m1,int j2,int m2,int j3,int m3){
  if (m1+m2 != m3) return 0.0;
  double pre = csqrt_((2.0*j3+1.0) * cfact_(j3+j1-j2)*cfact_(j3-j1+j2)*cfact_(j1+j2-j3)/cfact_(j1+j2+j3+1));
  pre *= csqrt_(cfact_(j3+m3)*cfact_(j3-m3)*cfact_(j1-m1)*cfact_(j1+m1)*cfact_(j2-m2)*cfact_(j2+m2));
  double s=0.0;
  for(int k=0;k<=j1+j2+j3;++k){
    int a1=k, a2=j1+j2-j3-k, a3=j1-m1-k, a4=j2+m2-k, a5=j3-j2+m1+k, a6=j3-j1-m2+k;
    if(a1<0||a2<0||a3<0||a4<0||a5<0||a6<0) continue;
    double d = cfact_(a1)*cfact_(a2)*cfact_(a3)*cfact_(a4)*cfact_(a5)*cfact_(a6);
    s += ((k&1)? -1.0:1.0)/d;
  }
  return pre*s;
}

struct C2d { double r, i; };
// U[a][ic] for Y^R = U @ Y^C; each row has <=2 nonzeros at ic in {a, 2l-a}
constexpr C2d uent_(int l, int a, int ic){
  const double s = 0.70710678118654752440;
  int m = a - l;
  if(m==0) return (ic==l)? C2d{1.0,0.0} : C2d{0.0,0.0};
  if(m>0){
    if(ic==a)     return C2d{ (m&1)? -s : s, 0.0};
    if(ic==2*l-a) return C2d{ s, 0.0};
    return C2d{0.0,0.0};
  }
  int aa = -m;
  if(ic==a)     return C2d{0.0, s};
  if(ic==2*l-a) return C2d{0.0, (aa&1)? s : -s};
  return C2d{0.0,0.0};
}

struct CGT { float v[343]; };

template<int L1,int L2,int L3>
constexpr CGT make_cg_(){
  constexpr int d1=2*L1+1, d2=2*L2+1, d3=2*L3+1;
  double cgv[d1*d2] = {};
  for(int i=0;i<d1;++i) for(int j=0;j<d2;++j){
    int m1=i-L1, m2=j-L2, m3=m1+m2;
    cgv[i*d2+j] = (m3>=-L3 && m3<=L3) ? ccg_(L1,m1,L2,m2,L3,m3) : 0.0;
  }
  double Tr[d1*d2*d3]={}, Ti[d1*d2*d3]={};
  double sr=0.0, si=0.0;
  for(int a=0;a<d1;++a) for(int bb=0;bb<d2;++bb) for(int c=0;c<d3;++c){
    double tr=0.0, ti=0.0;
    for(int s1=0;s1<2;++s1){
      int ic = s1? 2*L1-a : a;
      if(s1 && ic==a) continue;
      C2d A = uent_(L1,a,ic);
      if(A.r==0.0 && A.i==0.0) continue;
      for(int s2=0;s2<2;++s2){
        int jc = s2? 2*L2-bb : bb;
        if(s2 && jc==bb) continue;
        C2d Bc = uent_(L2,bb,jc);
        if(Bc.r==0.0 && Bc.i==0.0) continue;
        int m1=ic-L1, m2=jc-L2, m3=m1+m2;
        if(m3<-L3||m3>L3) continue;
        C2d Cc = uent_(L3,c,m3+L3);   // take conj below
        if(Cc.r==0.0 && Cc.i==0.0) continue;
        double cg = cgv[ic*d2+jc];
        double abr = A.r*Bc.r - A.i*Bc.i;
        double abi = A.r*Bc.i + A.i*Bc.r;
        tr += (abr*Cc.r + abi*Cc.i)*cg;   // Re(ab * conj(C))
        ti += (abi*Cc.r - abr*Cc.i)*cg;   // Im(ab * conj(C))
      }
    }
    int e=(a*d2+bb)*d3+c;
    Tr[e]=tr; Ti[e]=ti;
    sr += (tr<0.0? -tr:tr); si += (ti<0.0? -ti:ti);
  }
  CGT o{};
  bool re = (sr>=si);
  for(int e=0;e<d1*d2*d3;++e) o.v[e] = (float)(re? Tr[e] : Ti[e]);
  return o;
}

template<int A,int B,int C> struct CGH { static constexpr CGT t = make_cg_<A,B,C>(); };

constexpr CGT get_cg_(int l1,int l2,int l3){
  if(l1==0){
    if(l2==0) return CGH<0,0,0>::t;
    if(l2==1) return CGH<0,1,1>::t;
    if(l2==2) return CGH<0,2,2>::t;
    return CGH<0,3,3>::t;
  }
  if(l1==1){
    if(l3==0) return CGH<1,1,0>::t;
    if(l3==1){ if(l2==0) return CGH<1,0,1>::t; if(l2==1) return CGH<1,1,1>::t; return CGH<1,2,1>::t; }
    if(l3==2){ if(l2==1) return CGH<1,1,2>::t; if(l2==2) return CGH<1,2,2>::t; return CGH<1,3,2>::t; }
    { if(l2==2) return CGH<1,2,3>::t; return CGH<1,3,3>::t; }
  }
  if(l1==2){
    if(l3==0) return CGH<2,2,0>::t;
    if(l3==1){ if(l2==1) return CGH<2,1,1>::t; if(l2==2) return CGH<2,2,1>::t; return CGH<2,3,1>::t; }
    if(l3==2){ if(l2==0) return CGH<2,0,2>::t; if(l2==1) return CGH<2,1,2>::t; if(l2==2) return CGH<2,2,2>::t; return CGH<2,3,2>::t; }
    { if(l2==1) return CGH<2,1,3>::t; if(l2==2) return CGH<2,2,3>::t; return CGH<2,3,3>::t; }
  }
  {
    if(l3==0) return CGH<3,3,0>::t;
    if(l3==1){ if(l2==2) return CGH<3,2,1>::t; return CGH<3,3,1>::t; }
    if(l3==2){ if(l2==1) return CGH<3,1,2>::t; if(l2==2) return CGH<3,2,2>::t; return CGH<3,3,2>::t; }
    { if(l2==0) return CGH<3,0,3>::t; if(l2==1) return CGH<3,1,3>::t; if(l2==2) return CGH<3,2,3>::t; return CGH<3,3,3>::t; }
  }
}

// ---------------- constexpr bucketed sparse tables ----------------
// t-item u32: waddr(11) | base(7)<<11 | listbase<<18
// o-item u16: prel<<9 | u<<3 | o
template<int NTC,int NCC,int NOC>
struct BT {
  unsigned titem[NTC];
  float coef[NCC];
  unsigned short aidx[NCC];
  unsigned short oitem[NOC];
  int nt4, nt48, nt, nc, no, ok;
};

template<int PB,int PE,int CIN,int NTC,int NCC,int NOC>
constexpr BT<NTC,NCC,NOC> build_class_(){
  BT<NTC,NCC,NOC> bt{};
  PTable pt = build_paths();
  int lb_[160]={}; int pl_[160]={};
  int nc=0, ok=1;
  for(int p=PB;p<PE;++p){
    PathC pc = pt.p[p];
    int dli=2*pc.li+1, dlf=2*pc.lf+1, dlo=2*pc.lo+1, foff=pc.lf*pc.lf;
    CGT t = get_cg_(pc.li,pc.lf,pc.lo);
    for(int o=0;o<dlo;++o){
      int lidx = pc.pobase + o;
      int start = nc;
      for(int i=0;i<dli;++i) for(int f=0;f<dlf;++f){
        double val = (double)t.v[(i*dlf+f)*dlo+o];
        if(val>1e-12 || val<-1e-12){
          if(nc<NCC){ bt.coef[nc]=(float)val; bt.aidx[nc]=(unsigned short)((foff+f)*CIN+i); }
          else ok=0;
          ++nc;
        }
      }
      int len = nc-start;
      int plen = len<=4?4 : (len<=8?8:16);
      if(len>16) ok=0;
      for(int nn=len;nn<plen;++nn){ if(nc<NCC){ bt.coef[nc]=0.f; bt.aidx[nc]=0; } else ok=0; ++nc; }
      lb_[lidx]=start; pl_[lidx]=plen;
    }
  }
  bt.nc=nc; if(nc>NCC) ok=0;
  int nt=0;
  for(int pass=0;pass<3;++pass){
    int want = pass==0?4 : (pass==1?8:16);
    for(int p=PB;p<PE;++p){
      PathC pc = pt.p[p];
      int dli=2*pc.li+1, dlo=2*pc.lo+1;
      for(int o=0;o<dlo;++o){
        int lidx = pc.pobase + o;
        if(pl_[lidx]!=want) continue;
        for(int v=0;v<pc.mi;++v){
          unsigned waddr=(unsigned)(pc.toff + o*pc.mi + v);
          unsigned base =(unsigned)(pc.ci0 + v*dli);
          if(nt<NTC) bt.titem[nt] = waddr | (base<<11) | ((unsigned)lb_[lidx]<<18);
          ++nt;
        }
      }
    }
    if(pass==0) bt.nt4=nt;
    if(pass==1) bt.nt48=nt;
  }
  bt.nt=nt; if(nt!=NTC) ok=0;
  int no=0;
  for(int p=PB;p<PE;++p){
    PathC pc = pt.p[p]; int dlo=2*pc.lo+1;
    for(int u=0;u<pc.mo;++u) for(int o=0;o<dlo;++o){
      if(no<NOC) bt.oitem[no]=(unsigned short)(((p-PB)<<9)|(u<<3)|o);
      ++no;
    }
  }
  bt.no=no; if(no!=NOC) ok=0;
  bt.ok=ok;
  return bt;
}

constexpr auto BL0v  = build_class_<0,4,32,  512, 128, 152>();
constexpr auto BL12v = build_class_<4,38,128,1460,2560,1236>();
static_assert(BL0v.ok==1,  "L0 table overflow");
static_assert(BL12v.ok==1, "L12 table overflow");
static_assert(BL0v.nt4==512, "L0 all len<=4");
__constant__ BT<512,128,152>   c_BL0  = BL0v;
__constant__ BT<1460,2560,1236> c_BL12 = BL12v;

// ---------------- stage T bucket helper ----------------
template<int PL>
__device__ __forceinline__ void bucketT_(const unsigned* __restrict__ ti,
                                         const float* __restrict__ cf,
                                         const unsigned short* __restrict__ cx,
                                         const float* sA, float* sT,
                                         int i0, int i1, int tid){
  for(int i=i0+tid; i<i1; i+=256){
    unsigned e = ti[i];
    int waddr = e & 2047;
    int base  = (e>>11)&127;
    int lb    = (int)(e>>18);
    float s = 0.f;
    #pragma unroll
    for(int n=0;n<PL;++n)
      s += cf[lb+n] * sA[(int)cx[lb+n] + base];
    sT[waddr] = s;
  }
}

// ---------------- per-layer kernel (k-split: blockIdx.y in {0,1}) ----------------
template<int L>
__global__ __launch_bounds__(256) void layer_kernel(
    const float* __restrict__ fin, const int* __restrict__ z, const float* __restrict__ table,
    const float* __restrict__ pos, const float* __restrict__ maskp,
    const float* __restrict__ rw, float* __restrict__ pout)
{
  constexpr int C_IN = (L==0)?32:128;
  constexpr int PBEG = (L==0)?0:(L==1?4:38);
  constexpr int NT   = (L==0)?512:1460;
  constexpr int NO   = (L==0)?152:1236;
  constexpr int NT4  = (L==0)?BL0v.nt4 :BL12v.nt4;
  constexpr int NT48 = (L==0)?BL0v.nt48:BL12v.nt48;
  constexpr int NI_O = (NO+255)/256;

  __shared__ __align__(16) float s_fin[NA*C_IN];
  __shared__ __align__(16) float s_A[16*C_IN];
  __shared__ __align__(16) float s_T[NT];
  __shared__ float s_Y[NA*16];
  __shared__ float s_rb[NA*10];
  __shared__ float s_out[C_OUT];

  const int tid = threadIdx.x;
  const int b = blockIdx.x / NA, a = blockIdx.x % NA;
  const int kbase = blockIdx.y * 5;

  const unsigned* TI; const float* CF; const unsigned short* CX; const unsigned short* OT;
  if constexpr(L==0){ TI=c_BL0.titem;  CF=c_BL0.coef;  CX=c_BL0.aidx;  OT=c_BL0.oitem; }
  else              { TI=c_BL12.titem; CF=c_BL12.coef; CX=c_BL12.aidx; OT=c_BL12.oitem; }

  // ---- prologue ----
  if(tid < C_OUT) s_out[tid] = 0.f;

  if(tid < 240){   // rb: (j,k) parallel
    int j = tid/10, k = tid - 10*(tid/10);
    const float* pa = pos + (b*NA+a)*3;
    const float* pj = pos + (b*NA+j)*3;
    float dx=pj[0]-pa[0], dy=pj[1]-pa[1], dz=pj[2]-pa[2];
    float r = sqrtf(dx*dx+dy*dy+dz*dz + 1e-12f);
    float ck = 5.f*(float)k/9.f;
    float tt = (r-ck)*(9.f/5.f);
    s_rb[j*10+k] = expf(-0.5f*tt*tt)*maskp[b*NA+j];
  }
  if(tid < NA){    // Y: per j
    const int j = tid;
    const float* pa = pos + (b*NA+a)*3;
    const float* pj = pos + (b*NA+j)*3;
    float dx=pj[0]-pa[0], dy=pj[1]-pa[1], dz=pj[2]-pa[2];
    float r = sqrtf(dx*dx+dy*dy+dz*dz + 1e-12f);
    float inv = 1.f/(r + 1e-9f);
    float x=dx*inv, y=dy*inv, zz=dz*inv;
    float r2 = x*x+y*y+zz*zz;
    float* Yp = s_Y + j*16;
    Yp[0] = 0.28209479177387814f;
    Yp[1] = 0.4886025119029199f*y;
    Yp[2] = 0.4886025119029199f*zz;
    Yp[3] = 0.4886025119029199f*x;
    Yp[4] = 1.0925484305920792f*x*y;
    Yp[5] = 1.0925484305920792f*y*zz;
    Yp[6] = 0.31539156525252005f*(3.f*zz*zz - r2);
    Yp[7] = 1.0925484305920792f*x*zz;
    Yp[8] = 0.5462742152960396f*(x*x - y*y);
    Yp[9] = 0.5900435899266435f*y*(3.f*x*x - y*y);
    Yp[10]= 2.890611442640554f*x*y*zz;
    Yp[11]= 0.4570457994644658f*y*(5.f*zz*zz - r2);
    Yp[12]= 0.3731763325901154f*zz*(5.f*zz*zz - 3.f*r2);
    Yp[13]= 0.4570457994644658f*x*(5.f*zz*zz - r2);
    Yp[14]= 1.445305721320277f*zz*(x*x - y*y);
    Yp[15]= 0.5900435899266435f*x*(x*x - 3.f*y*y);
  }

  if(L==0){
    for(int i=tid;i<NA*EMBED;i+=256){
      int j = i>>5, c = i&31;
      s_fin[i] = table[z[b*NA+j]*EMBED + c];
    }
  } else {
    const float4* fg = reinterpret_cast<const float4*>(fin + b*NA*C_IN);
    float4* fs = reinterpret_cast<float4*>(s_fin);
    #pragma unroll
    for(int r=0;r<(NA*C_IN/4+255)/256;++r){
      int i = tid + r*256;
      if(i < NA*C_IN/4) fs[i] = fg[i];
    }
  }

  // out-item register decode
  int wb[NI_O], momi[NI_O], mi4_[NI_O], t4b[NI_O];
  float acc[NI_O];
  #pragma unroll
  for(int r=0;r<NI_O;++r){
    acc[r]=0.f; wb[r]=-1; momi[r]=0; mi4_[r]=0; t4b[r]=0;
    int idx = tid + r*256;
    if(idx < NO){
      unsigned e = OT[idx];
      int prel=e>>9, u=(e>>3)&63, o=e&7;
      const PathC pc = c_paths.p[prel+PBEG];
      wb[r]=pc.woff + u*pc.mi; momi[r]=pc.mo*pc.mi; mi4_[r]=pc.mi>>2;
      t4b[r]=(pc.toff + o*pc.mi)>>2;
    }
  }

  const float4* fs4 = reinterpret_cast<const float4*>(s_fin);
  float4* sA4 = reinterpret_cast<float4*>(s_A);

  // stage A on one 128-thread half (alternating by local kk parity)
  auto stageA = [&](int k, int half){
    bool active = half ? (tid>=128) : (tid<128);
    if(!active) return;
    const int g = tid & 127;
    if(L==0){
      int f = g>>3, c4 = g&7;
      float4 s0 = {0.f,0.f,0.f,0.f};
      #pragma unroll
      for(int j=0;j<NA;++j){
        float ry = s_rb[j*10+k]*s_Y[j*16+f];
        float4 v = fs4[j*8 + c4];
        s0.x += ry*v.x; s0.y += ry*v.y; s0.z += ry*v.z; s0.w += ry*v.w;
      }
      sA4[f*8 + c4] = s0;
    } else {
      int f0 = g>>5, c4 = g&31;     // rows f0, f0+4, f0+8, f0+12
      float4 a0={0,0,0,0}, a1={0,0,0,0}, a2={0,0,0,0}, a3={0,0,0,0};
      #pragma unroll
      for(int j=0;j<NA;++j){
        float rbv = s_rb[j*10+k];
        float y0 = rbv*s_Y[j*16+f0];
        float y1 = rbv*s_Y[j*16+f0+4];
        float y2 = rbv*s_Y[j*16+f0+8];
        float y3 = rbv*s_Y[j*16+f0+12];
        float4 v = fs4[j*32 + c4];
        a0.x += y0*v.x; a0.y += y0*v.y; a0.z += y0*v.z; a0.w += y0*v.w;
        a1.x += y1*v.x; a1.y += y1*v.y; a1.z += y1*v.z; a1.w += y1*v.w;
        a2.x += y2*v.x; a2.y += y2*v.y; a2.z += y2*v.z; a2.w += y2*v.w;
        a3.x += y3*v.x; a3.y += y3*v.y; a3.z += y3*v.z; a3.w += y3*v.w;
      }
      sA4[(f0   )*32 + c4] = a0;
      sA4[(f0+ 4)*32 + c4] = a1;
      sA4[(f0+ 8)*32 + c4] = a2;
      sA4[(f0+12)*32 + c4] = a3;
    }
  };

  __syncthreads();
  stageA(kbase, 0);
  __syncthreads();

  // ---- k pipeline over this block's 5 radial bases ----
  for(int kk=0;kk<5;++kk){
    const int k = kbase + kk;
    // stage T: fully-unrolled fixed-length sparse contractions
    bucketT_<4 >(TI, CF, CX, s_A, s_T, 0,    NT4,  tid);
    bucketT_<8 >(TI, CF, CX, s_A, s_T, NT4,  NT48, tid);
    bucketT_<16>(TI, CF, CX, s_A, s_T, NT48, NT,   tid);
    __syncthreads();

    // stage out: acc += sum_v W[k,u,v] * T[o][v]; overlap next stage A
    #pragma unroll
    for(int r=0;r<NI_O;++r){
      if(wb[r] >= 0){
        const float4* Wp = reinterpret_cast<const float4*>(rw + wb[r] + k*momi[r]);
        const float4* Tp = reinterpret_cast<const float4*>(s_T) + t4b[r];
        float s = 0.f;
        for(int v4=0; v4<mi4_[r]; ++v4){
          float4 w = Wp[v4], t = Tp[v4];
          s += w.x*t.x + w.y*t.y + w.z*t.z + w.w*t.w;
        }
        acc[r] += s;
      }
    }
    if(kk<4) stageA(k+1, (kk+1)&1);
    __syncthreads();
  }

  // ---- reduce path contributions ----
  #pragma unroll
  for(int r=0;r<NI_O;++r){
    if(wb[r] >= 0){
      int idx = tid + r*256;
      unsigned e = OT[idx];
      int prel=e>>9, u=(e>>3)&63, o=e&7;
      const PathC pc = c_paths.p[prel+PBEG];
      atomicAdd(&s_out[pc.obase + u*(2*pc.lo+1) + o], acc[r]*pc.scale);
    }
  }
  __syncthreads();

  if(tid < C_OUT)
    pout[(blockIdx.y*NB*NA + b*NA + a)*C_OUT + tid] = s_out[tid];
}

// ---------------- epilogue: combine k-slices, gate, mask ----------------
__global__ __launch_bounds__(192) void epi_kernel(const float* __restrict__ part,
    const float* __restrict__ maskp, float* __restrict__ fout){
  __shared__ float so[C_OUT];
  __shared__ float sg[24];
  const int ba = blockIdx.x, t = threadIdx.x;
  if(t < C_OUT) so[t] = part[ba*C_OUT + t] + part[(NB*NA)*C_OUT + ba*C_OUT + t];
  __syncthreads();
  if(t < 24) sg[t] = 1.f/(1.f+expf(-so[24+t]));
  __syncthreads();
  if(t < C_FEAT){
    float val;
    if(t<24)       { val = fmaxf(so[t], 0.f); }
    else if(t<60)  { int r=t-24;  int v=r/3; val = so[48+r]  * sg[v]; }
    else if(t<100) { int r=t-60;  int v=r/5; val = so[84+r]  * sg[12+v]; }
    else           { int r=t-100; int v=r/7; val = so[124+r] * sg[20+v]; }
    fout[ba*C_FEAT + t] = val*maskp[ba];
  }
}

// ---------------- launch ----------------
extern "C" void kernel_launch(void* const* d_in, const int* in_sizes, int n_in,
                              void* d_out, int out_size, void* d_ws, size_t ws_size,
                              hipStream_t stream) {
  const int*   z     = (const int*)  d_in[0];
  const float* pos   = (const float*)d_in[1];
  const float* mask  = (const float*)d_in[2];
  const float* table = (const float*)d_in[3];
  const float* rw    = (const float*)d_in[4];
  float* out = (float*)d_out;
  float* ws  = (float*)d_ws;

  float* ps = ws;                    // 2*768*152 = 233472 floats
  float* fA = ps + 2*NB*NA*C_OUT;    // 768*128
  float* fB = fA + NB*NA*C_FEAT;

  dim3 g2(NB*NA, 2);
  layer_kernel<0><<<g2, 256, 0, stream>>>(nullptr, z, table, pos, mask, rw, ps);
  epi_kernel<<<NB*NA, 192, 0, stream>>>(ps, mask, fA);
  layer_kernel<1><<<g2, 256, 0, stream>>>(fA, z, table, pos, mask, rw, ps);
  epi_kernel<<<NB*NA, 192, 0, stream>>>(ps, mask, fB);
  layer_kernel<2><<<g2, 256, 0, stream>>>(fB, z, table, pos, mask, rw, ps);
  epi_kernel<<<NB*NA, 192, 0, stream>>>(ps, mask, out);
}